// Round 3
// baseline (3040.715 us; speedup 1.0000x reference)
//
#include <hip/hip_runtime.h>
#include <math.h>

#define NPTS   131072
#define FEAT   64
#define KCLUS  2048
#define KHALF  1024      // clusters per blockIdx.y split
#define CHUNKC 256       // clusters staged per LDS chunk (== blockDim)

typedef __attribute__((ext_vector_type(8))) short frag_ab;   // 8 bf16
typedef __attribute__((ext_vector_type(4))) float frag_cd;   // 4 fp32 acc

// fp32 -> bf16 RNE
__device__ __forceinline__ short f2bf(float f) {
    unsigned u = __float_as_uint(f);
    u += 0x7FFFu + ((u >> 16) & 1u);
    return (short)(u >> 16);
}
// monotone float<->u32 (handles negatives): order(float) == order(unsigned)
__device__ __forceinline__ unsigned fmono(float e) {
    unsigned u = __float_as_uint(e);
    return u ^ (unsigned)(((int)u >> 31) | 0x80000000);
}
__device__ __forceinline__ float fmono_dec(unsigned m) {
    unsigned u = (m & 0x80000000u) ? (m ^ 0x80000000u) : ~m;
    return __uint_as_float(u);
}

// Exact fp32 (cn - 2 x.c) with round-2's FMA order; lexicographic-min (d,k)
// via monotone u64 atomicMin.
__device__ __forceinline__ void exact_refine(const float* __restrict__ x,
                                             const float* __restrict__ c,
                                             float cnv, int p, int kk,
                                             unsigned long long* best) {
    const float4* xr4 = (const float4*)&x[(size_t)p * FEAT];
    const float4* cr4 = (const float4*)&c[(size_t)kk * FEAT];
    float s = 0.f;
#pragma unroll
    for (int j = 0; j < 16; ++j) {
        float4 a4 = xr4[j], b4 = cr4[j];
        s = fmaf(a4.x, b4.x, s); s = fmaf(a4.y, b4.y, s);
        s = fmaf(a4.z, b4.z, s); s = fmaf(a4.w, b4.w, s);
    }
    float e = fmaf(-2.f, s, cnv);
    unsigned long long key = ((unsigned long long)fmono(e) << 32) | (unsigned)kk;
    atomicMin(best + p, key);
}

// ---------------------------------------------------------------------------
// cprep: cnorm (exact fp32), cbs_t = bf16(-2c) in part-major [part][k][8] layout
// (part = feature/8), cmax = max ||c||.
// ---------------------------------------------------------------------------
__global__ void cprep_kernel(const float* __restrict__ c, float* __restrict__ cnorm,
                             short* __restrict__ cbs_t, float* __restrict__ cmax) {
    int k = blockIdx.x * blockDim.x + threadIdx.x;
    if (k >= KCLUS) return;
    const float4* row = (const float4*)&c[k * FEAT];
    float s = 0.f;
#pragma unroll
    for (int j = 0; j < 16; ++j) {
        float4 v = row[j];
        s = fmaf(v.x, v.x, s); s = fmaf(v.y, v.y, s);
        s = fmaf(v.z, v.z, s); s = fmaf(v.w, v.w, s);
        short4 b;
        b.x = f2bf(-2.f * v.x); b.y = f2bf(-2.f * v.y);
        b.z = f2bf(-2.f * v.z); b.w = f2bf(-2.f * v.w);
        *(short4*)&cbs_t[((size_t)(j >> 1) * KCLUS + k) * 8 + (j & 1) * 4] = b;
    }
    cnorm[k] = s;
    atomicMax((int*)cmax, __float_as_int(sqrtf(s)));  // positive floats: int max == float max
}

__global__ void xprep_kernel(const float* __restrict__ x, float* __restrict__ xn) {
    int p = blockIdx.x * blockDim.x + threadIdx.x;
    const float4* row = (const float4*)&x[(size_t)p * FEAT];
    float s = 0.f;
#pragma unroll
    for (int j = 0; j < 16; ++j) {
        float4 v = row[j];
        s = fmaf(v.x, v.x, s); s = fmaf(v.y, v.y, s);
        s = fmaf(v.z, v.z, s); s = fmaf(v.w, v.w, s);
    }
    xn[p] = sqrtf(s);
}

// ---------------------------------------------------------------------------
// Shared A-fragment loader: lane holds A[m=lane&15][k=q*8+j], 4 row-tiles.
// ---------------------------------------------------------------------------
__device__ __forceinline__ void load_A(const float* __restrict__ x, int pt0,
                                       int col, int q, frag_ab A[4][2]) {
#pragma unroll
    for (int rt = 0; rt < 4; ++rt)
#pragma unroll
        for (int kh = 0; kh < 2; ++kh) {
            const float4* xp = (const float4*)&x[(size_t)(pt0 + rt * 16 + col) * FEAT + kh * 32 + q * 8];
            float4 v0 = xp[0], v1 = xp[1];
            frag_ab a;
            a[0] = f2bf(v0.x); a[1] = f2bf(v0.y); a[2] = f2bf(v0.z); a[3] = f2bf(v0.w);
            a[4] = f2bf(v1.x); a[5] = f2bf(v1.y); a[6] = f2bf(v1.z); a[7] = f2bf(v1.w);
            A[rt][kh] = a;
        }
}

// ---------------------------------------------------------------------------
// PASS 1: approx min only. grid (512, 2); blockIdx.y picks cluster half.
// acc initialized with cn -> distance falls out of the MFMA directly.
// ---------------------------------------------------------------------------
__global__ __launch_bounds__(256) void pass1_kernel(
    const float* __restrict__ x, const short* __restrict__ cbs_t,
    const float* __restrict__ cnorm, unsigned* __restrict__ pmin)
{
    __shared__ short csh[8 * CHUNKC * 8];   // part-major [part][lc][8] -- conflict-free
    __shared__ float cnsh[CHUNKC];

    const int tid = threadIdx.x, wv = tid >> 6, lane = tid & 63;
    const int col = lane & 15, q = lane >> 4;
    const int pt0 = blockIdx.x * 256 + wv * 64;
    const int kbase = blockIdx.y * KHALF;

    frag_ab A[4][2];
    load_A(x, pt0, col, q, A);

    float m[4][4];
#pragma unroll
    for (int rt = 0; rt < 4; ++rt)
#pragma unroll
        for (int r = 0; r < 4; ++r) m[rt][r] = INFINITY;

    for (int k0 = 0; k0 < KHALF; k0 += CHUNKC) {
        __syncthreads();
#pragma unroll
        for (int p8 = 0; p8 < 8; ++p8)     // contiguous global -> contiguous LDS
            *(frag_ab*)&csh[(p8 * CHUNKC + tid) * 8] =
                *(const frag_ab*)&cbs_t[((size_t)p8 * KCLUS + kbase + k0 + tid) * 8];
        cnsh[tid] = cnorm[kbase + k0 + tid];
        __syncthreads();

#pragma unroll 4
        for (int ct = 0; ct < CHUNKC / 16; ++ct) {
            const int lc = ct * 16 + col;
            frag_ab b0 = *(const frag_ab*)&csh[(q * CHUNKC + lc) * 8];
            frag_ab b1 = *(const frag_ab*)&csh[((4 + q) * CHUNKC + lc) * 8];
            const float cnv = cnsh[lc];
#pragma unroll
            for (int rt = 0; rt < 4; ++rt) {
                frag_cd acc = {cnv, cnv, cnv, cnv};
                acc = __builtin_amdgcn_mfma_f32_16x16x32_bf16(A[rt][0], b0, acc, 0, 0, 0);
                acc = __builtin_amdgcn_mfma_f32_16x16x32_bf16(A[rt][1], b1, acc, 0, 0, 0);
                m[rt][0] = fminf(m[rt][0], acc[0]);
                m[rt][1] = fminf(m[rt][1], acc[1]);
                m[rt][2] = fminf(m[rt][2], acc[2]);
                m[rt][3] = fminf(m[rt][3], acc[3]);
            }
        }
    }

#pragma unroll
    for (int rt = 0; rt < 4; ++rt)
#pragma unroll
        for (int r = 0; r < 4; ++r) {
            float mm = m[rt][r];
            mm = fminf(mm, __shfl_xor(mm, 1));
            mm = fminf(mm, __shfl_xor(mm, 2));
            mm = fminf(mm, __shfl_xor(mm, 4));
            mm = fminf(mm, __shfl_xor(mm, 8));
            if (col == 0)
                atomicMin(&pmin[pt0 + rt * 16 + q * 4 + r], fmono(mm));
        }
}

// ---------------------------------------------------------------------------
// PASS 2: same MFMA; ballot-compact (p,k) candidates with d~ <= min + margin.
// Margin 0.033*||x||*max||c|| rigorously covers 2x the bf16 dot error.
// ---------------------------------------------------------------------------
__global__ __launch_bounds__(256) void pass2_kernel(
    const float* __restrict__ x, const float* __restrict__ c,
    const short* __restrict__ cbs_t, const float* __restrict__ cnorm,
    const float* __restrict__ xn, const float* __restrict__ cmaxp,
    const unsigned* __restrict__ pmin,
    unsigned* __restrict__ buf, unsigned* __restrict__ cnt, unsigned cap,
    unsigned long long* __restrict__ best)
{
    __shared__ short csh[8 * CHUNKC * 8];
    __shared__ float cnsh[CHUNKC];

    const int tid = threadIdx.x, wv = tid >> 6, lane = tid & 63;
    const int col = lane & 15, q = lane >> 4;
    const int pt0 = blockIdx.x * 256 + wv * 64;
    const int kbase = blockIdx.y * KHALF;

    frag_ab A[4][2];
    load_A(x, pt0, col, q, A);

    const float cmax = *cmaxp;
    float t[4][4];
#pragma unroll
    for (int rt = 0; rt < 4; ++rt)
#pragma unroll
        for (int r = 0; r < 4; ++r) {
            const int p = pt0 + rt * 16 + q * 4 + r;
            t[rt][r] = fmono_dec(pmin[p]) + 0.033f * xn[p] * cmax;
        }

    for (int k0 = 0; k0 < KHALF; k0 += CHUNKC) {
        __syncthreads();
#pragma unroll
        for (int p8 = 0; p8 < 8; ++p8)
            *(frag_ab*)&csh[(p8 * CHUNKC + tid) * 8] =
                *(const frag_ab*)&cbs_t[((size_t)p8 * KCLUS + kbase + k0 + tid) * 8];
        cnsh[tid] = cnorm[kbase + k0 + tid];
        __syncthreads();

#pragma unroll 2
        for (int ct = 0; ct < CHUNKC / 16; ++ct) {
            const int lc = ct * 16 + col;
            frag_ab b0 = *(const frag_ab*)&csh[(q * CHUNKC + lc) * 8];
            frag_ab b1 = *(const frag_ab*)&csh[((4 + q) * CHUNKC + lc) * 8];
            const float cnv = cnsh[lc];
            const int kk = kbase + k0 + lc;
#pragma unroll
            for (int rt = 0; rt < 4; ++rt) {
                frag_cd acc = {cnv, cnv, cnv, cnv};
                acc = __builtin_amdgcn_mfma_f32_16x16x32_bf16(A[rt][0], b0, acc, 0, 0, 0);
                acc = __builtin_amdgcn_mfma_f32_16x16x32_bf16(A[rt][1], b1, acc, 0, 0, 0);
#pragma unroll
                for (int r = 0; r < 4; ++r) {
                    bool rec = acc[r] <= t[rt][r];
                    unsigned long long msk = __ballot(rec);
                    if (msk) {                                   // wave-uniform
                        int ldr = __ffsll(msk) - 1;
                        unsigned base = 0;
                        int rank = __popcll(msk & ((1ull << lane) - 1ull));
                        if (lane == ldr)
                            base = atomicAdd(cnt, (unsigned)__popcll(msk));
                        base = __shfl(base, ldr);
                        if (rec) {
                            unsigned idx = base + (unsigned)rank;
                            const int p = pt0 + rt * 16 + q * 4 + r;
                            if (idx < cap)
                                buf[idx] = ((unsigned)p << 11) | (unsigned)kk;
                            else
                                exact_refine(x, c, cnv, p, kk, best);  // overflow fallback
                        }
                    }
                }
            }
        }
    }
}

// ---------------------------------------------------------------------------
// refine: one candidate per thread, exact fp32, atomicMin into best keys.
// ---------------------------------------------------------------------------
__global__ void refine_kernel(const float* __restrict__ x, const float* __restrict__ c,
                              const float* __restrict__ cnorm,
                              const unsigned* __restrict__ buf,
                              const unsigned* __restrict__ cntp, unsigned cap,
                              unsigned long long* __restrict__ best) {
    unsigned n = *cntp;
    if (n > cap) n = cap;
    const unsigned stride = gridDim.x * blockDim.x;
    for (unsigned i = blockIdx.x * blockDim.x + threadIdx.x; i < n; i += stride) {
        unsigned code = buf[i];
        int p = (int)(code >> 11), k = (int)(code & 2047u);
        exact_refine(x, c, cnorm[k], p, k, best);
    }
}

// ---------------------------------------------------------------------------
// finalize: decode assignments + wave-transposed scatter (lane = feature).
// ---------------------------------------------------------------------------
__global__ void finalize_scatter(const float* __restrict__ x,
                                 const unsigned long long* __restrict__ best,
                                 float* __restrict__ out_assign,
                                 float* __restrict__ sums, int* __restrict__ counts) {
    const int lane = threadIdx.x & 63;
    const int wv = threadIdx.x >> 6;
    const int pbase = blockIdx.x * 256 + wv * 64;

    int myk = (int)(best[pbase + lane] & 2047ull);
    out_assign[pbase + lane] = (float)myk;          // coalesced

#pragma unroll 1
    for (int p = 0; p < 64; ++p) {
        int a = __shfl(myk, p);
        float xv = x[(size_t)(pbase + p) * FEAT + lane];
        atomicAdd(&sums[a * FEAT + lane], xv);
        if (lane == 0) atomicAdd(&counts[a], 1);
    }
}

__global__ void update_kernel(const float* __restrict__ c,
                              const float* __restrict__ sums,
                              const int* __restrict__ counts,
                              float* __restrict__ out_upd) {
    int i = blockIdx.x * blockDim.x + threadIdx.x;
    if (i < KCLUS * FEAT) {
        int   k   = i >> 6;
        float cv  = c[i];
        int   cnt = counts[k];
        float nc  = (cnt > 0) ? (sums[i] / (float)cnt) : cv;
        out_upd[i] = 0.99f * cv + 0.01f * nc;
    }
}

extern "C" void kernel_launch(void* const* d_in, const int* in_sizes, int n_in,
                              void* d_out, int out_size, void* d_ws, size_t ws_size,
                              hipStream_t stream) {
    const float* x = (const float*)d_in[0];
    const float* c = (const float*)d_in[1];

    float* out        = (float*)d_out;
    float* out_assign = out;          // [0, N): assignments as float
    float* out_upd    = out + NPTS;   // [N, N + K*FEAT)

    char* ws = (char*)d_ws;
    // layout (bytes):
    constexpr size_t O_CNORM = 0;                       // 8 KB
    constexpr size_t O_XN    = 8192;                    // 512 KB
    constexpr size_t O_CBS   = 532480;                  // 256 KB (part-major bf16 -2c)
    constexpr size_t O_ZERO  = 794624;                  // cmax(4) cnt(4) sums(512K) counts(8K)
    constexpr size_t O_CMAX  = 794624;
    constexpr size_t O_CNT   = 794628;
    constexpr size_t O_SUMS  = 794632;
    constexpr size_t O_CNTS  = 794632 + 524288;         // 1318920
    constexpr size_t ZERO_LEN = 8 + 524288 + 8192;
    constexpr size_t O_PMIN  = 1327112;                 // 512 KB, init 0xFF
    constexpr size_t O_BEST  = 1327112 + 524288;        // 1 MB,  init 0xFF
    constexpr size_t FF_LEN  = 524288 + 1048576;
    constexpr size_t O_BUF   = O_BEST + 1048576;        // 2899976: candidate codes

    float*    cnorm  = (float*)(ws + O_CNORM);
    float*    xn     = (float*)(ws + O_XN);
    short*    cbs_t  = (short*)(ws + O_CBS);
    float*    cmax   = (float*)(ws + O_CMAX);
    unsigned* cnt    = (unsigned*)(ws + O_CNT);
    float*    sums   = (float*)(ws + O_SUMS);
    int*      counts = (int*)(ws + O_CNTS);
    unsigned* pmin   = (unsigned*)(ws + O_PMIN);
    unsigned long long* best = (unsigned long long*)(ws + O_BEST);
    unsigned* buf    = (unsigned*)(ws + O_BUF);

    unsigned cap = 0;
    if (ws_size > O_BUF + 16) {
        size_t c64 = (ws_size - O_BUF) / 4;
        cap = (c64 > 0x400000) ? 0x400000u : (unsigned)c64;   // <= 4M entries (16 MB)
    }

    hipMemsetAsync(ws + O_ZERO, 0, ZERO_LEN, stream);
    hipMemsetAsync(ws + O_PMIN, 0xFF, FF_LEN, stream);

    cprep_kernel<<<KCLUS / 256, 256, 0, stream>>>(c, cnorm, cbs_t, cmax);
    xprep_kernel<<<NPTS / 256, 256, 0, stream>>>(x, xn);
    pass1_kernel<<<dim3(NPTS / 256, 2), 256, 0, stream>>>(x, cbs_t, cnorm, pmin);
    pass2_kernel<<<dim3(NPTS / 256, 2), 256, 0, stream>>>(x, c, cbs_t, cnorm, xn, cmax,
                                                          pmin, buf, cnt, cap, best);
    refine_kernel<<<512, 256, 0, stream>>>(x, c, cnorm, buf, cnt, cap, best);
    finalize_scatter<<<NPTS / 256, 256, 0, stream>>>(x, best, out_assign, sums, counts);
    update_kernel<<<(KCLUS * FEAT) / 256, 256, 0, stream>>>(c, sums, counts, out_upd);
}

// Round 7
// 335.758 us; speedup vs baseline: 9.0563x; 9.0563x over previous
//
#include <hip/hip_runtime.h>
#include <math.h>

#define NPTS    131072
#define FEAT    64
#define KCLUS   2048
#define CHUNKC  256      // clusters staged per LDS chunk (== blockDim)
#define PPW     32       // points per wave (2 MFMA row-tiles)
#define WPB     4        // waves per 256-thread block (wave = 64 on CDNA!)
#define PPB     (PPW * WPB)   // 128 points per block
#define CANDC   10       // per-lane register candidate slots

typedef __attribute__((ext_vector_type(8))) short frag_ab;   // 8 bf16
typedef __attribute__((ext_vector_type(4))) float frag_cd;   // 4 fp32 acc

// fp32 -> bf16 RNE
__device__ __forceinline__ short f2bf(float f) {
    unsigned u = __float_as_uint(f);
    u += 0x7FFFu + ((u >> 16) & 1u);
    return (short)(u >> 16);
}

// Exact fp32 distance term (cn - 2 x.c): IDENTICAL single-chain FMA order to
// rounds 1-3 (empirically matches numpy argmin on this data, absmax 0 x3).
__device__ __forceinline__ float exact_dist(const float* __restrict__ x,
                                            const float* __restrict__ c,
                                            float cnv, int p, int kk) {
    const float4* xr4 = (const float4*)&x[(size_t)p * FEAT];
    const float4* cr4 = (const float4*)&c[(size_t)kk * FEAT];
    float s = 0.f;
#pragma unroll
    for (int j = 0; j < 16; ++j) {
        float4 a4 = xr4[j], b4 = cr4[j];
        s = fmaf(a4.x, b4.x, s); s = fmaf(a4.y, b4.y, s);
        s = fmaf(a4.z, b4.z, s); s = fmaf(a4.w, b4.w, s);
    }
    return fmaf(-2.f, s, cnv);
}

// ---------------------------------------------------------------------------
// cprep: exact fp32 cnorm, cbs_t = bf16(-2c) part-major [part=f/8][k][8]
// (round-3 proven: conflict-free staging + correct B layout), cmax = max||c||.
// ---------------------------------------------------------------------------
__global__ void cprep_kernel(const float* __restrict__ c, float* __restrict__ cnorm,
                             short* __restrict__ cbs_t, float* __restrict__ cmax) {
    int k = blockIdx.x * blockDim.x + threadIdx.x;
    if (k >= KCLUS) return;
    const float4* row = (const float4*)&c[k * FEAT];
    float s = 0.f;
#pragma unroll
    for (int j = 0; j < 16; ++j) {
        float4 v = row[j];
        s = fmaf(v.x, v.x, s); s = fmaf(v.y, v.y, s);
        s = fmaf(v.z, v.z, s); s = fmaf(v.w, v.w, s);
        short4 b;
        b.x = f2bf(-2.f * v.x); b.y = f2bf(-2.f * v.y);
        b.z = f2bf(-2.f * v.z); b.w = f2bf(-2.f * v.w);
        *(short4*)&cbs_t[((size_t)(j >> 1) * KCLUS + k) * 8 + (j & 1) * 4] = b;
    }
    cnorm[k] = s;
    atomicMax((int*)cmax, __float_as_int(sqrtf(s)));  // positive: int-max == float-max
}

// xn[p] = ||x_p||  (round-2 proven)
__global__ void xprep_kernel(const float* __restrict__ x, float* __restrict__ xn) {
    int p = blockIdx.x * blockDim.x + threadIdx.x;
    const float4* row = (const float4*)&x[(size_t)p * FEAT];
    float s = 0.f;
#pragma unroll
    for (int j = 0; j < 16; ++j) {
        float4 v = row[j];
        s = fmaf(v.x, v.x, s); s = fmaf(v.y, v.y, s);
        s = fmaf(v.z, v.z, s); s = fmaf(v.w, v.w, s);
    }
    xn[p] = sqrtf(s);
}

// ---------------------------------------------------------------------------
// Assign: pass 1 (MFMA approx min, registers) -> threshold -> pass 2 (MFMA +
// per-lane REGISTER candidate capture) -> post-loop exact fp32 refine ->
// round-2's cross-lane (d,k) reduce + col==0 write.
// Block = 256 threads = 4 WAVES; each wave covers PPW=32 points -> 128/block.
// ---------------------------------------------------------------------------
__global__ __launch_bounds__(256) void assign_kernel(
    const float* __restrict__ x, const float* __restrict__ c,
    const short* __restrict__ cbs_t, const float* __restrict__ cnorm,
    const float* __restrict__ xn, const float* __restrict__ cmaxp,
    float* __restrict__ out_assign)
{
    __shared__ short csh[8 * CHUNKC * 8];   // 32 KB part-major staging
    __shared__ float cnsh[CHUNKC];          // 1 KB

    const int tid = threadIdx.x, wv = tid >> 6, lane = tid & 63;
    const int col = lane & 15, q = lane >> 4;
    const int pt0 = blockIdx.x * PPB + wv * PPW;   // FIXED: 128 pts/block, grid NPTS/128

    // A-frags: lane holds A[m=lane&15][k=q*8+j] (round-2/3 proven layout).
    frag_ab A[2][2];
#pragma unroll
    for (int rt = 0; rt < 2; ++rt)
#pragma unroll
        for (int kh = 0; kh < 2; ++kh) {
            const float4* xp = (const float4*)&x[(size_t)(pt0 + rt * 16 + col) * FEAT + kh * 32 + q * 8];
            float4 v0 = xp[0], v1 = xp[1];
            frag_ab a;
            a[0] = f2bf(v0.x); a[1] = f2bf(v0.y); a[2] = f2bf(v0.z); a[3] = f2bf(v0.w);
            a[4] = f2bf(v1.x); a[5] = f2bf(v1.y); a[6] = f2bf(v1.z); a[7] = f2bf(v1.w);
            A[rt][kh] = a;
        }

    float m[2][4];
#pragma unroll
    for (int rt = 0; rt < 2; ++rt)
#pragma unroll
        for (int r = 0; r < 4; ++r) m[rt][r] = INFINITY;

    // ------------------- PASS 1: approx min (registers only) --------------
    for (int k0 = 0; k0 < KCLUS; k0 += CHUNKC) {
        __syncthreads();
#pragma unroll
        for (int p8 = 0; p8 < 8; ++p8)
            *(frag_ab*)&csh[(p8 * CHUNKC + tid) * 8] =
                *(const frag_ab*)&cbs_t[((size_t)p8 * KCLUS + k0 + tid) * 8];
        cnsh[tid] = cnorm[k0 + tid];
        __syncthreads();

#pragma unroll 4
        for (int ct = 0; ct < CHUNKC / 16; ++ct) {
            const int lc = ct * 16 + col;
            frag_ab b0 = *(const frag_ab*)&csh[(q * CHUNKC + lc) * 8];
            frag_ab b1 = *(const frag_ab*)&csh[((4 + q) * CHUNKC + lc) * 8];
            const float cnv = cnsh[lc];
#pragma unroll
            for (int rt = 0; rt < 2; ++rt) {
                frag_cd acc = {cnv, cnv, cnv, cnv};
                acc = __builtin_amdgcn_mfma_f32_16x16x32_bf16(A[rt][0], b0, acc, 0, 0, 0);
                acc = __builtin_amdgcn_mfma_f32_16x16x32_bf16(A[rt][1], b1, acc, 0, 0, 0);
                m[rt][0] = fminf(m[rt][0], acc[0]);
                m[rt][1] = fminf(m[rt][1], acc[1]);
                m[rt][2] = fminf(m[rt][2], acc[2]);
                m[rt][3] = fminf(m[rt][3], acc[3]);
            }
        }
    }

    // Threshold (round-2 proven form): m~ + 0.034*||x||*cmax >= m~ + 2*eps_bf16.
    const float cmax = *cmaxp;
    float t[2][4];
#pragma unroll
    for (int rt = 0; rt < 2; ++rt)
#pragma unroll
        for (int r = 0; r < 4; ++r) {
            float mm = m[rt][r];
            mm = fminf(mm, __shfl_xor(mm, 1));
            mm = fminf(mm, __shfl_xor(mm, 2));
            mm = fminf(mm, __shfl_xor(mm, 4));
            mm = fminf(mm, __shfl_xor(mm, 8));
            t[rt][r] = mm + 0.034f * xn[pt0 + rt * 16 + q * 4 + r] * cmax;
        }

    // ------------------- PASS 2: per-lane register capture -----------------
    unsigned codes[CANDC];
    int ccnt = 0;

    for (int k0 = 0; k0 < KCLUS; k0 += CHUNKC) {
        __syncthreads();
#pragma unroll
        for (int p8 = 0; p8 < 8; ++p8)
            *(frag_ab*)&csh[(p8 * CHUNKC + tid) * 8] =
                *(const frag_ab*)&cbs_t[((size_t)p8 * KCLUS + k0 + tid) * 8];
        cnsh[tid] = cnorm[k0 + tid];
        __syncthreads();

#pragma unroll 2
        for (int ct = 0; ct < CHUNKC / 16; ++ct) {
            const int lc = ct * 16 + col;
            frag_ab b0 = *(const frag_ab*)&csh[(q * CHUNKC + lc) * 8];
            frag_ab b1 = *(const frag_ab*)&csh[((4 + q) * CHUNKC + lc) * 8];
            const float cnv = cnsh[lc];
            const int kk = k0 + lc;
#pragma unroll
            for (int rt = 0; rt < 2; ++rt) {
                frag_cd acc = {cnv, cnv, cnv, cnv};
                acc = __builtin_amdgcn_mfma_f32_16x16x32_bf16(A[rt][0], b0, acc, 0, 0, 0);
                acc = __builtin_amdgcn_mfma_f32_16x16x32_bf16(A[rt][1], b1, acc, 0, 0, 0);
#pragma unroll
                for (int r = 0; r < 4; ++r) {
                    if (acc[r] <= t[rt][r]) {   // rare
                        unsigned code = ((unsigned)(rt * 16 + q * 4 + r) << 11) | (unsigned)kk;
#pragma unroll
                        for (int s = 0; s < CANDC; ++s)   // register-file push
                            if (s == ccnt) codes[s] = code;
                        ccnt++;
                    }
                }
            }
        }
    }

    // ------------------- exact refine (per-lane, registers) ----------------
    const bool anyovf = __any(ccnt > CANDC);

    if (!anyovf) {
        float bestd[2][4];
        int   bestk[2][4];
#pragma unroll
        for (int rt = 0; rt < 2; ++rt)
#pragma unroll
            for (int r = 0; r < 4; ++r) { bestd[rt][r] = INFINITY; bestk[rt][r] = 0x7fffffff; }

        for (int i = 0; i < CANDC; ++i) {
            if (i < ccnt) {
                unsigned code = codes[i];
                int pl = (int)(code >> 11), kk = (int)(code & 2047u);
                float e = exact_dist(x, c, cnorm[kk], pt0 + pl, kk);
                int crt = pl >> 4, cr = pl & 3;
#pragma unroll
                for (int rt = 0; rt < 2; ++rt)
#pragma unroll
                    for (int r = 0; r < 4; ++r)
                        if (crt == rt && cr == r &&
                            (e < bestd[rt][r] || (e == bestd[rt][r] && kk < bestk[rt][r]))) {
                            bestd[rt][r] = e; bestk[rt][r] = kk;
                        }
            }
        }

        // Round-2 verbatim cross-lane (d,k) reduce + col==0 float4 write.
#pragma unroll
        for (int rt = 0; rt < 2; ++rt) {
#pragma unroll
            for (int r = 0; r < 4; ++r) {
                float bd = bestd[rt][r]; int bk = bestk[rt][r];
#pragma unroll
                for (int mask = 1; mask <= 8; mask <<= 1) {
                    float od = __shfl_xor(bd, mask);
                    int   ok = __shfl_xor(bk, mask);
                    if (od < bd || (od == bd && ok < bk)) { bd = od; bk = ok; }
                }
                bestd[rt][r] = bd; bestk[rt][r] = bk;
            }
            if (col == 0) {
                float4 w = { (float)bestk[rt][0], (float)bestk[rt][1],
                             (float)bestk[rt][2], (float)bestk[rt][3] };
                *(float4*)&out_assign[pt0 + rt * 16 + q * 4] = w;
            }
        }
    } else {
        // Overflow (rare): whole-wave fully-exact argmin, no thresholds.
        for (int pp = 0; pp < PPW; ++pp) {
            const int p = pt0 + pp;
            float bd = INFINITY; int bk = 0x7fffffff;
            for (int kk = lane; kk < KCLUS; kk += 64) {
                float e = exact_dist(x, c, cnorm[kk], p, kk);
                if (e < bd || (e == bd && kk < bk)) { bd = e; bk = kk; }
            }
#pragma unroll
            for (int mask = 1; mask <= 32; mask <<= 1) {
                float od = __shfl_xor(bd, mask);
                int   ok = __shfl_xor(bk, mask);
                if (od < bd || (od == bd && ok < bk)) { bd = od; bk = ok; }
            }
            if (lane == 0) out_assign[p] = (float)bk;
        }
    }
}

// ---------------------------------------------------------------------------
// Wave-transposed scatter (round-2 verbatim, proven): lane = feature,
// one coalesced 256B atomic row per point.
// ---------------------------------------------------------------------------
__global__ void scatter_kernel(const float* __restrict__ x,
                               const float* __restrict__ assign_f,
                               float* __restrict__ sums, int* __restrict__ counts) {
    const int lane  = threadIdx.x & 63;
    const int wv    = threadIdx.x >> 6;
    const int pbase = blockIdx.x * 256 + wv * 64;
#pragma unroll 1
    for (int p = 0; p < 64; ++p) {
        int   a  = (int)assign_f[pbase + p];
        float xv = x[(size_t)(pbase + p) * FEAT + lane];
        atomicAdd(&sums[a * FEAT + lane], xv);
        if (lane == 0) atomicAdd(&counts[a], 1);
    }
}

__global__ void update_kernel(const float* __restrict__ c,
                              const float* __restrict__ sums,
                              const int* __restrict__ counts,
                              float* __restrict__ out_upd) {
    int i = blockIdx.x * blockDim.x + threadIdx.x;
    if (i < KCLUS * FEAT) {
        int   k   = i >> 6;
        float cv  = c[i];
        int   cnt = counts[k];
        float nc  = (cnt > 0) ? (sums[i] / (float)cnt) : cv;
        out_upd[i] = 0.99f * cv + 0.01f * nc;
    }
}

extern "C" void kernel_launch(void* const* d_in, const int* in_sizes, int n_in,
                              void* d_out, int out_size, void* d_ws, size_t ws_size,
                              hipStream_t stream) {
    const float* x = (const float*)d_in[0];
    const float* c = (const float*)d_in[1];

    float* out        = (float*)d_out;
    float* out_assign = out;          // [0, N): assignments as float
    float* out_upd    = out + NPTS;   // [N, N + K*FEAT)

    // Workspace ~1.3 MB (round-2-proven scale).
    char* ws = (char*)d_ws;
    constexpr size_t O_CNORM = 0;                  // 8 KB
    constexpr size_t O_XN    = 8192;               // 512 KB
    constexpr size_t O_CBS   = 8192 + 524288;      // 256 KB part-major bf16(-2c)
    constexpr size_t O_ZERO  = O_CBS + 262144;     // cmax(64B) sums(512K) counts(8K)
    constexpr size_t O_CMAX  = O_ZERO;
    constexpr size_t O_SUMS  = O_ZERO + 64;
    constexpr size_t O_CNTS  = O_SUMS + 524288;
    constexpr size_t ZERO_LEN = 64 + 524288 + 8192;

    float* cnorm  = (float*)(ws + O_CNORM);
    float* xn     = (float*)(ws + O_XN);
    short* cbs_t  = (short*)(ws + O_CBS);
    float* cmax   = (float*)(ws + O_CMAX);
    float* sums   = (float*)(ws + O_SUMS);
    int*   counts = (int*)(ws + O_CNTS);

    hipMemsetAsync(ws + O_ZERO, 0, ZERO_LEN, stream);

    cprep_kernel<<<KCLUS / 256, 256, 0, stream>>>(c, cnorm, cbs_t, cmax);
    xprep_kernel<<<NPTS / 256, 256, 0, stream>>>(x, xn);
    // 4 waves/block x 32 pts/wave = 128 pts/block -> grid NPTS/128 (wave=64!)
    assign_kernel<<<NPTS / PPB, 256, 0, stream>>>(x, c, cbs_t, cnorm, xn, cmax, out_assign);
    scatter_kernel<<<NPTS / 256, 256, 0, stream>>>(x, out_assign, sums, counts);
    update_kernel<<<(KCLUS * FEAT) / 256, 256, 0, stream>>>(c, sums, counts, out_upd);
}